// Round 1
// baseline (283.172 us; speedup 1.0000x reference)
//
#include <hip/hip_runtime.h>

#define BB 4
#define NV 4096
#define CC 64
#define HH 376
#define WW 1240
#define LDT 72   // padded LDS row stride in ushorts (16B-aligned, ~2-way conflicts)

typedef __bf16 bf16x8 __attribute__((ext_vector_type(8)));
typedef float  f32x4  __attribute__((ext_vector_type(4)));

static __device__ __forceinline__ unsigned short f2bf(float x) {
  unsigned int u = __float_as_uint(x);
  unsigned int r = (u + 0x7fffu + ((u >> 16) & 1u)) >> 16;  // RNE
  return (unsigned short)r;
}

// ---------------- W2 = fc_w @ o_w, b2 = fc_w @ o_b ----------------
__global__ __launch_bounds__(256) void kw2(const float* __restrict__ ow,
                                           const float* __restrict__ ob,
                                           const float* __restrict__ fc,
                                           float* __restrict__ W2,
                                           float* __restrict__ b2) {
  int idx = blockIdx.x * blockDim.x + threadIdx.x;  // 0..4095
  if (idx >= CC * CC) return;
  int i = idx >> 6, j = idx & 63;
  float acc = 0.f;
  for (int k = 0; k < CC; ++k) acc += fc[i * CC + k] * ow[k * CC + j];
  W2[idx] = acc;
  if (idx < CC) {
    float a = 0.f;
    for (int k = 0; k < CC; ++k) a += fc[idx * CC + k] * ob[k];
    b2[idx] = a;
  }
}

// ---------------- prep: gather + Q/K/V projections + passthrough ----------------
__global__ __launch_bounds__(64) void kprep(
    const float* __restrict__ vfeat, const float* __restrict__ v3d,
    const float* __restrict__ img, const int* __restrict__ vx,
    const int* __restrict__ vy, const float* __restrict__ qw,
    const float* __restrict__ qb, const float* __restrict__ kw,
    const float* __restrict__ kb, const float* __restrict__ vw,
    const float* __restrict__ vb, float* __restrict__ out,
    unsigned short* __restrict__ Qb, unsigned short* __restrict__ Kb,
    unsigned short* __restrict__ VTb) {
  int idx = blockIdx.x * blockDim.x + threadIdx.x;
  if (idx >= BB * NV) return;
  int b = idx >> 12;
  int n = idx & (NV - 1);
  size_t row = (size_t)b * NV + n;

  // voxel features: passthrough + V projection (store V transposed, bf16)
  const float4* vf4 = (const float4*)(vfeat + row * CC);
  float4 vr[16];
#pragma unroll
  for (int i = 0; i < 16; ++i) vr[i] = vf4[i];
  float4* out4 = (float4*)(out + row * 128);
#pragma unroll
  for (int i = 0; i < 16; ++i) out4[i] = vr[i];

  for (int c = 0; c < CC; ++c) {
    float acc = vb[c];
    const float4* w4 = (const float4*)(vw + c * CC);
#pragma unroll
    for (int j = 0; j < 16; ++j) {
      float4 w = w4[j];
      acc += vr[j].x * w.x + vr[j].y * w.y + vr[j].z * w.z + vr[j].w * w.w;
    }
    VTb[((size_t)b * CC + c) * NV + n] = f2bf(acc);
  }

  // K projection (3 -> 64)
  float a0 = v3d[row * 3 + 0], a1 = v3d[row * 3 + 1], a2 = v3d[row * 3 + 2];
  unsigned int* K32 = (unsigned int*)(Kb + row * CC);
  for (int c = 0; c < CC; c += 2) {
    float k0 = a0 * kw[c * 3 + 0] + a1 * kw[c * 3 + 1] + a2 * kw[c * 3 + 2] + kb[c];
    float k1 = a0 * kw[c * 3 + 3] + a1 * kw[c * 3 + 4] + a2 * kw[c * 3 + 5] + kb[c + 1];
    K32[c >> 1] = (unsigned int)f2bf(k0) | ((unsigned int)f2bf(k1) << 16);
  }

  // camera gather + Q projection (scaled by 1/8)
  int x = vx[row], y = vy[row];
  bool valid = (x >= 0) & (x < WW) & (y >= 0) & (y < HH);
  float cam[CC];
  if (valid) {
    const float* ib = img + (size_t)b * CC * (HH * WW) + (size_t)y * WW + x;
#pragma unroll
    for (int c = 0; c < CC; ++c) cam[c] = ib[(size_t)c * (HH * WW)];
  } else {
#pragma unroll
    for (int c = 0; c < CC; ++c) cam[c] = 0.f;
  }
  unsigned int* Q32 = (unsigned int*)(Qb + row * CC);
  for (int c = 0; c < CC; c += 2) {
    float acc0 = qb[c], acc1 = qb[c + 1];
#pragma unroll
    for (int j = 0; j < CC; ++j) {
      acc0 += cam[j] * qw[c * CC + j];
      acc1 += cam[j] * qw[(c + 1) * CC + j];
    }
    acc0 *= 0.125f;
    acc1 *= 0.125f;
    Q32[c >> 1] = (unsigned int)f2bf(acc0) | ((unsigned int)f2bf(acc1) << 16);
  }
}

// ---------------- flash attention: 4 waves/block, 16 q/wave, 64-key tiles ----------------
__global__ __launch_bounds__(256) void kattn(const unsigned short* __restrict__ Qb,
                                             const unsigned short* __restrict__ Kb,
                                             const unsigned short* __restrict__ VTb,
                                             float* __restrict__ ctx) {
  __shared__ unsigned short Ks[64 * LDT];
  __shared__ unsigned short Vs[64 * LDT];
  __shared__ unsigned short Ps[4][16 * LDT];

  const int b = blockIdx.y;
  const int q0 = blockIdx.x * 64;
  const int tid = threadIdx.x;
  const int wid = tid >> 6;
  const int lane = tid & 63;
  const int lq = lane & 15;  // this lane's query (softmax role) / frag row
  const int lg = lane >> 4;  // lane group 0..3

  const unsigned short* qp = Qb + ((size_t)b * NV + q0 + wid * 16 + lq) * CC + lg * 8;
  bf16x8 qf0 = *(const bf16x8*)(qp);
  bf16x8 qf1 = *(const bf16x8*)(qp + 32);

  const f32x4 vzero = {0.f, 0.f, 0.f, 0.f};
  float m_run = -1e30f, l_run = 0.f;
  f32x4 oacc[4];  // oacc[t][r] = O[q = 4*lg + r][d = 16*t + lq]
#pragma unroll
  for (int t = 0; t < 4; ++t) oacc[t] = vzero;

  const int srow = tid >> 2;        // 0..63
  const int scol = (tid & 3) * 16;  // 0,16,32,48
  const unsigned short* kgb = Kb + ((size_t)b * NV) * CC;
  const unsigned short* vgb = VTb + (size_t)b * CC * NV;

  for (int k0 = 0; k0 < NV; k0 += 64) {
    {  // stage K tile (keys x dims) and V^T tile (dims x keys)
      const uint4* ksrc = (const uint4*)(kgb + (size_t)(k0 + srow) * CC + scol);
      uint4* kdst = (uint4*)&Ks[srow * LDT + scol];
      kdst[0] = ksrc[0];
      kdst[1] = ksrc[1];
      const uint4* vsrc = (const uint4*)(vgb + (size_t)srow * NV + k0 + scol);
      uint4* vdst = (uint4*)&Vs[srow * LDT + scol];
      vdst[0] = vsrc[0];
      vdst[1] = vsrc[1];
    }
    __syncthreads();

    // S^T = K . Q^T  -> lane holds scores for query lq, keys 16t + 4lg + r
    f32x4 s[4];
#pragma unroll
    for (int t = 0; t < 4; ++t) s[t] = vzero;
#pragma unroll
    for (int t = 0; t < 4; ++t) {
      bf16x8 ka0 = *(const bf16x8*)&Ks[(t * 16 + lq) * LDT + lg * 8];
      bf16x8 ka1 = *(const bf16x8*)&Ks[(t * 16 + lq) * LDT + 32 + lg * 8];
      s[t] = __builtin_amdgcn_mfma_f32_16x16x32_bf16(ka0, qf0, s[t], 0, 0, 0);
      s[t] = __builtin_amdgcn_mfma_f32_16x16x32_bf16(ka1, qf1, s[t], 0, 0, 0);
    }

    // online softmax
    float tmax = s[0][0];
#pragma unroll
    for (int t = 0; t < 4; ++t)
#pragma unroll
      for (int r = 0; r < 4; ++r) tmax = fmaxf(tmax, s[t][r]);
    tmax = fmaxf(tmax, __shfl_xor(tmax, 16));
    tmax = fmaxf(tmax, __shfl_xor(tmax, 32));
    float m_new = fmaxf(m_run, tmax);
    float sc = __expf(m_run - m_new);
    l_run *= sc;
    m_run = m_new;

    float psum = 0.f;
#pragma unroll
    for (int t = 0; t < 4; ++t) {
#pragma unroll
      for (int r = 0; r < 4; ++r) {
        float p = __expf(s[t][r] - m_new);
        psum += p;
        Ps[wid][lq * LDT + t * 16 + lg * 4 + r] = f2bf(p);
      }
    }
    psum += __shfl_xor(psum, 16);
    psum += __shfl_xor(psum, 32);
    l_run += psum;

    // rescale O rows (query of row r is 4*lg + r; its sc lives in lane 4*lg+r)
#pragma unroll
    for (int r = 0; r < 4; ++r) {
      float scr = __shfl(sc, lg * 4 + r);
#pragma unroll
      for (int t = 0; t < 4; ++t) oacc[t][r] *= scr;
    }

    // O += P . V   (A = P from per-wave LDS, B = V^T fragments)
#pragma unroll
    for (int ks = 0; ks < 2; ++ks) {
      bf16x8 pa = *(const bf16x8*)&Ps[wid][lq * LDT + ks * 32 + lg * 8];
#pragma unroll
      for (int t = 0; t < 4; ++t) {
        bf16x8 vbf = *(const bf16x8*)&Vs[(t * 16 + lq) * LDT + ks * 32 + lg * 8];
        oacc[t] = __builtin_amdgcn_mfma_f32_16x16x32_bf16(pa, vbf, oacc[t], 0, 0, 0);
      }
    }
    __syncthreads();
  }

  // ctx = O / l
#pragma unroll
  for (int r = 0; r < 4; ++r) {
    float lr = __shfl(l_run, lg * 4 + r);
    float inv = 1.f / lr;
    float* cp = ctx + ((size_t)b * NV + q0 + wid * 16 + lg * 4 + r) * CC + lq;
#pragma unroll
    for (int t = 0; t < 4; ++t) cp[t * 16] = oacc[t][r] * inv;
  }
}

// ---------------- epilogue: fused = relu(ctx @ W2^T + b2) ----------------
__global__ __launch_bounds__(64) void kepi(const float* __restrict__ ctx,
                                           const float* __restrict__ W2,
                                           const float* __restrict__ b2,
                                           float* __restrict__ out) {
  int idx = blockIdx.x * blockDim.x + threadIdx.x;
  if (idx >= BB * NV) return;
  size_t row = (size_t)idx;
  const float4* c4 = (const float4*)(ctx + row * CC);
  float4 cr[16];
#pragma unroll
  for (int i = 0; i < 16; ++i) cr[i] = c4[i];
  float* op = out + row * 128 + CC;
  for (int i = 0; i < CC; ++i) {
    float acc = b2[i];
    const float4* w4 = (const float4*)(W2 + i * CC);
#pragma unroll
    for (int j = 0; j < 16; ++j) {
      float4 w = w4[j];
      acc += cr[j].x * w.x + cr[j].y * w.y + cr[j].z * w.z + cr[j].w * w.w;
    }
    op[i] = fmaxf(acc, 0.f);
  }
}

extern "C" void kernel_launch(void* const* d_in, const int* in_sizes, int n_in,
                              void* d_out, int out_size, void* d_ws, size_t ws_size,
                              hipStream_t stream) {
  const float* vfeat = (const float*)d_in[0];
  const float* v3d = (const float*)d_in[1];
  const float* img = (const float*)d_in[2];
  const int* vx = (const int*)d_in[3];
  const int* vy = (const int*)d_in[4];
  const float* qw = (const float*)d_in[5];
  const float* qb = (const float*)d_in[6];
  const float* kw = (const float*)d_in[7];
  const float* kb = (const float*)d_in[8];
  const float* vw = (const float*)d_in[9];
  const float* vb = (const float*)d_in[10];
  const float* ow = (const float*)d_in[11];
  const float* ob = (const float*)d_in[12];
  const float* fc = (const float*)d_in[13];
  float* out = (float*)d_out;

  char* ws = (char*)d_ws;
  unsigned short* Qb = (unsigned short*)ws;                 // 2 MB
  unsigned short* Kb = Qb + (size_t)BB * NV * CC;           // 2 MB
  unsigned short* VTb = Kb + (size_t)BB * NV * CC;          // 2 MB
  float* ctx = (float*)(VTb + (size_t)BB * NV * CC);        // 4 MB
  float* W2 = ctx + (size_t)BB * NV * CC;                   // 16 KB
  float* b2 = W2 + CC * CC;

  kw2<<<16, 256, 0, stream>>>(ow, ob, fc, W2, b2);
  kprep<<<256, 64, 0, stream>>>(vfeat, v3d, img, vx, vy, qw, qb, kw, kb, vw, vb,
                                out, Qb, Kb, VTb);
  kattn<<<dim3(64, BB), 256, 0, stream>>>(Qb, Kb, VTb, ctx);
  kepi<<<256, 64, 0, stream>>>(ctx, W2, b2, out);
}

// Round 3
// 152.667 us; speedup vs baseline: 1.8548x; 1.8548x over previous
//
#include <hip/hip_runtime.h>

#define BB 4
#define NV 4096
#define CC 64
#define HH 376
#define WW 1240
#define HW (HH * WW)
#define LDT 72   // padded LDS row stride in ushorts -> minimal b128 bank conflict
#define NT (NV / 64)

typedef __bf16 bf16x8 __attribute__((ext_vector_type(8)));
typedef float  f32x4  __attribute__((ext_vector_type(4)));

static __device__ __forceinline__ unsigned short f2bf(float x) {
  unsigned int u = __float_as_uint(x);
  unsigned int r = (u + 0x7fffu + ((u >> 16) & 1u)) >> 16;  // RNE
  return (unsigned short)r;
}
static __device__ __forceinline__ unsigned int pk2bf(float a, float b) {
  return (unsigned int)f2bf(a) | ((unsigned int)f2bf(b) << 16);
}

// ---------------- W2 = fc_w @ o_w, b2 = fc_w @ o_b ----------------
__global__ __launch_bounds__(256) void kw2(const float* __restrict__ ow,
                                           const float* __restrict__ ob,
                                           const float* __restrict__ fc,
                                           float* __restrict__ W2,
                                           float* __restrict__ b2) {
  int idx = blockIdx.x * blockDim.x + threadIdx.x;
  if (idx >= CC * CC) return;
  int i = idx >> 6, j = idx & 63;
  float acc = 0.f;
  for (int k = 0; k < CC; ++k) acc += fc[i * CC + k] * ow[k * CC + j];
  W2[idx] = acc;
  if (idx < CC) {
    float a = 0.f;
    for (int k = 0; k < CC; ++k) a += fc[idx * CC + k] * ob[k];
    b2[idx] = a;
  }
}

// ---------------- prep: gather + Q/K/V projections + passthrough ----------------
// 256 threads/block, 64 voxels/block, 4 threads per voxel (16-channel slice each).
__global__ __launch_bounds__(256) void kprep(
    const float* __restrict__ vfeat, const float* __restrict__ v3d,
    const float* __restrict__ img, const int* __restrict__ vx,
    const int* __restrict__ vy, const float* __restrict__ qw,
    const float* __restrict__ qb, const float* __restrict__ kw,
    const float* __restrict__ kb, const float* __restrict__ vw,
    const float* __restrict__ vb, float* __restrict__ out,
    unsigned short* __restrict__ Qb, unsigned short* __restrict__ Kb,
    unsigned short* __restrict__ VTb) {
  __shared__ float VfS[64][68];
  __shared__ float CamS[64][68];
  const int tid = threadIdx.x;
  const int vl = tid >> 2;       // voxel-local 0..63
  const int p = tid & 3;         // channel-slice 0..3
  const int gv = blockIdx.x * 64 + vl;
  const int b = gv >> 12, n = gv & (NV - 1);
  const size_t row = (size_t)b * NV + n;

  // vfeat slice: passthrough + LDS stash
  {
    const float4* vf4 = (const float4*)(vfeat + row * CC) + p * 4;
    float4* o4 = (float4*)(out + row * 128) + p * 4;
    float4* s4 = (float4*)&VfS[vl][p * 16];
#pragma unroll
    for (int i = 0; i < 4; ++i) { float4 t = vf4[i]; o4[i] = t; s4[i] = t; }
  }

  // camera gather, channels [16p, 16p+16)
  {
    int x = vx[row], y = vy[row];
    bool valid = (x >= 0) & (x < WW) & (y >= 0) & (y < HH);
    int xs = valid ? x : 0, ys = valid ? y : 0;
    const float* ib = img + ((size_t)b * CC + p * 16) * (size_t)HW + (size_t)ys * WW + xs;
#pragma unroll
    for (int i = 0; i < 16; ++i) {
      float cv = ib[(size_t)i * HW];
      CamS[vl][p * 16 + i] = valid ? cv : 0.f;
    }
  }

  // K projection, channels [16p, 16p+16)
  {
    float a0 = v3d[row * 3 + 0], a1 = v3d[row * 3 + 1], a2 = v3d[row * 3 + 2];
    unsigned int* K32 = (unsigned int*)(Kb + row * CC) + p * 8;
#pragma unroll
    for (int cc = 0; cc < 16; cc += 2) {
      int c = p * 16 + cc;
      float k0 = fmaf(a0, kw[c * 3 + 0], fmaf(a1, kw[c * 3 + 1], fmaf(a2, kw[c * 3 + 2], kb[c])));
      float k1 = fmaf(a0, kw[c * 3 + 3], fmaf(a1, kw[c * 3 + 4], fmaf(a2, kw[c * 3 + 5], kb[c + 1])));
      K32[cc >> 1] = pk2bf(k0, k1);
    }
  }
  __syncthreads();

  // V projection, output channels [16p, 16p+16), store transposed bf16
  {
    f32x4 vr[16];
#pragma unroll
    for (int i = 0; i < 16; ++i) vr[i] = *(const f32x4*)&VfS[vl][i * 4];
#pragma unroll
    for (int cc = 0; cc < 16; ++cc) {
      int c = p * 16 + cc;
      const float4* w4 = (const float4*)(vw + c * CC);
      float acc = vb[c];
#pragma unroll
      for (int j = 0; j < 16; ++j) {
        float4 w = w4[j];
        acc = fmaf(vr[j][0], w.x, fmaf(vr[j][1], w.y, fmaf(vr[j][2], w.z, fmaf(vr[j][3], w.w, acc))));
      }
      VTb[((size_t)b * CC + c) * NV + n] = f2bf(acc);
    }
  }

  // Q projection (scaled 1/8), output channels [16p, 16p+16)
  {
    f32x4 cr[16];
#pragma unroll
    for (int i = 0; i < 16; ++i) cr[i] = *(const f32x4*)&CamS[vl][i * 4];
    unsigned int* Q32 = (unsigned int*)(Qb + row * CC) + p * 8;
#pragma unroll
    for (int cc = 0; cc < 16; cc += 2) {
      int c = p * 16 + cc;
      float acc0 = qb[c], acc1 = qb[c + 1];
      const float4* w0 = (const float4*)(qw + c * CC);
      const float4* w1 = (const float4*)(qw + (c + 1) * CC);
#pragma unroll
      for (int j = 0; j < 16; ++j) {
        f32x4 a = cr[j];
        float4 wa = w0[j], wb = w1[j];
        acc0 = fmaf(a[0], wa.x, fmaf(a[1], wa.y, fmaf(a[2], wa.z, fmaf(a[3], wa.w, acc0))));
        acc1 = fmaf(a[0], wb.x, fmaf(a[1], wb.y, fmaf(a[2], wb.z, fmaf(a[3], wb.w, acc1))));
      }
      Q32[cc >> 1] = pk2bf(acc0 * 0.125f, acc1 * 0.125f);
    }
  }
}

// ---------------- flash attention + fused epilogue ----------------
// 4 waves/block, 16 q/wave, 64-key tiles, double-buffered staging (2x uint4/thread).
__global__ __launch_bounds__(256) void kattn(const unsigned short* __restrict__ Qb,
                                             const unsigned short* __restrict__ Kb,
                                             const unsigned short* __restrict__ VTb,
                                             const float* __restrict__ W2f,
                                             const float* __restrict__ b2f,
                                             float* __restrict__ out) {
  __shared__ unsigned short Ks[2][64 * LDT];
  __shared__ unsigned short Vs[2][64 * LDT];
  __shared__ unsigned short Ps[4][16 * LDT];
  __shared__ unsigned short W2s[64 * LDT];
  __shared__ float b2s[64];

  const int bid = blockIdx.x;  // XCD-aware: xcd = bid%8 owns one (batch, q-half)
  const int b = (bid & 7) >> 1;
  const int q0 = (((bid & 1) << 5) + (bid >> 3)) << 6;
  const int tid = threadIdx.x;
  const int wid = tid >> 6;
  const int lane = tid & 63;
  const int lq = lane & 15;
  const int lg = lane >> 4;

  const int srow = tid >> 2;        // 0..63
  const int scol = (tid & 3) * 16;  // 16-ushort slot per thread (2x uint4)

  // stage W2 (bf16) + b2
  {
    const float4* wsrc = (const float4*)(W2f + srow * CC + scol);
    float4 f0 = wsrc[0], f1 = wsrc[1], f2 = wsrc[2], f3 = wsrc[3];
    uint4 u0 = {pk2bf(f0.x, f0.y), pk2bf(f0.z, f0.w), pk2bf(f1.x, f1.y), pk2bf(f1.z, f1.w)};
    uint4 u1 = {pk2bf(f2.x, f2.y), pk2bf(f2.z, f2.w), pk2bf(f3.x, f3.y), pk2bf(f3.z, f3.w)};
    uint4* wdst = (uint4*)&W2s[srow * LDT + scol];
    wdst[0] = u0;
    wdst[1] = u1;
    if (tid < 64) b2s[tid] = b2f[tid];
  }

  const unsigned short* qp = Qb + ((size_t)b * NV + q0 + wid * 16 + lq) * CC + lg * 8;
  bf16x8 qf0 = *(const bf16x8*)(qp);
  bf16x8 qf1 = *(const bf16x8*)(qp + 32);

  const f32x4 vzero = {0.f, 0.f, 0.f, 0.f};
  float m_run = -1e30f, l_run = 0.f;
  f32x4 oacc[4];
#pragma unroll
  for (int t = 0; t < 4; ++t) oacc[t] = vzero;

  const unsigned short* kgb = Kb + (size_t)b * NV * CC;
  const unsigned short* vgb = VTb + (size_t)b * CC * NV;

  uint4 kr0, kr1, vr0, vr1;
  // prologue: stage tile 0 into buf 0
  {
    const uint4* ksrc = (const uint4*)(kgb + (size_t)srow * CC + scol);
    const uint4* vsrc = (const uint4*)(vgb + (size_t)srow * NV + scol);
    kr0 = ksrc[0]; kr1 = ksrc[1];
    vr0 = vsrc[0]; vr1 = vsrc[1];
    uint4* kdst = (uint4*)&Ks[0][srow * LDT + scol];
    uint4* vdst = (uint4*)&Vs[0][srow * LDT + scol];
    kdst[0] = kr0; kdst[1] = kr1;
    vdst[0] = vr0; vdst[1] = vr1;
  }
  __syncthreads();

  int cur = 0;
  for (int t0 = 0; t0 < NT; ++t0) {
    // issue next tile's global loads early (latency hides under compute)
    if (t0 + 1 < NT) {
      int k0 = (t0 + 1) * 64;
      const uint4* ksrc = (const uint4*)(kgb + (size_t)(k0 + srow) * CC + scol);
      const uint4* vsrc = (const uint4*)(vgb + (size_t)srow * NV + k0 + scol);
      kr0 = ksrc[0]; kr1 = ksrc[1];
      vr0 = vsrc[0]; vr1 = vsrc[1];
    }

    // S^T = K . Q^T
    f32x4 s[4];
#pragma unroll
    for (int t = 0; t < 4; ++t) s[t] = vzero;
#pragma unroll
    for (int t = 0; t < 4; ++t) {
      bf16x8 ka0 = *(const bf16x8*)&Ks[cur][(t * 16 + lq) * LDT + lg * 8];
      bf16x8 ka1 = *(const bf16x8*)&Ks[cur][(t * 16 + lq) * LDT + 32 + lg * 8];
      s[t] = __builtin_amdgcn_mfma_f32_16x16x32_bf16(ka0, qf0, s[t], 0, 0, 0);
      s[t] = __builtin_amdgcn_mfma_f32_16x16x32_bf16(ka1, qf1, s[t], 0, 0, 0);
    }

    // online softmax (lane owns all scores of query lq within key range)
    float tmax = s[0][0];
#pragma unroll
    for (int t = 0; t < 4; ++t)
#pragma unroll
      for (int r = 0; r < 4; ++r) tmax = fmaxf(tmax, s[t][r]);
    tmax = fmaxf(tmax, __shfl_xor(tmax, 16));
    tmax = fmaxf(tmax, __shfl_xor(tmax, 32));
    float m_new = fmaxf(m_run, tmax);
    float sc = __expf(m_run - m_new);
    l_run *= sc;
    m_run = m_new;

    float psum = 0.f;
#pragma unroll
    for (int t = 0; t < 4; ++t) {
      float p0 = __expf(s[t][0] - m_new);
      float p1 = __expf(s[t][1] - m_new);
      float p2 = __expf(s[t][2] - m_new);
      float p3 = __expf(s[t][3] - m_new);
      psum += (p0 + p1) + (p2 + p3);
      unsigned int* pd = (unsigned int*)&Ps[wid][lq * LDT + t * 16 + lg * 4];
      pd[0] = pk2bf(p0, p1);
      pd[1] = pk2bf(p2, p3);
    }
    psum += __shfl_xor(psum, 16);
    psum += __shfl_xor(psum, 32);
    l_run += psum;

#pragma unroll
    for (int r = 0; r < 4; ++r) {
      float scr = __shfl(sc, lg * 4 + r);
#pragma unroll
      for (int t = 0; t < 4; ++t) oacc[t][r] *= scr;
    }

    // O += P . V
#pragma unroll
    for (int ks = 0; ks < 2; ++ks) {
      bf16x8 pa = *(const bf16x8*)&Ps[wid][lq * LDT + ks * 32 + lg * 8];
#pragma unroll
      for (int t = 0; t < 4; ++t) {
        bf16x8 vbf = *(const bf16x8*)&Vs[cur][(t * 16 + lq) * LDT + ks * 32 + lg * 8];
        oacc[t] = __builtin_amdgcn_mfma_f32_16x16x32_bf16(pa, vbf, oacc[t], 0, 0, 0);
      }
    }

    // write next tile into the other buffer (vmcnt wait lands here, not before compute)
    if (t0 + 1 < NT) {
      uint4* kdst = (uint4*)&Ks[cur ^ 1][srow * LDT + scol];
      uint4* vdst = (uint4*)&Vs[cur ^ 1][srow * LDT + scol];
      kdst[0] = kr0; kdst[1] = kr1;
      vdst[0] = vr0; vdst[1] = vr1;
    }
    __syncthreads();
    cur ^= 1;
  }

  // ---- fused epilogue: fused = relu(ctx @ W2^T + b2) ----
  // ctx (bf16, already /l) into per-wave LDS, reshaped [q][d]
#pragma unroll
  for (int r = 0; r < 4; ++r) {
    float lr = __shfl(l_run, lg * 4 + r);
    float inv = 1.f / lr;
#pragma unroll
    for (int t = 0; t < 4; ++t)
      Ps[wid][(lg * 4 + r) * LDT + t * 16 + lq] = f2bf(oacc[t][r] * inv);
  }

  bf16x8 cb0 = *(const bf16x8*)&Ps[wid][lq * LDT + lg * 8];
  bf16x8 cb1 = *(const bf16x8*)&Ps[wid][lq * LDT + 32 + lg * 8];
  float* orow = out + ((size_t)b * NV + q0 + wid * 16 + lq) * 128 + 64;
#pragma unroll
  for (int t2 = 0; t2 < 4; ++t2) {
    bf16x8 wa0 = *(const bf16x8*)&W2s[(t2 * 16 + lq) * LDT + lg * 8];
    bf16x8 wa1 = *(const bf16x8*)&W2s[(t2 * 16 + lq) * LDT + 32 + lg * 8];
    f32x4 r2 = vzero;
    r2 = __builtin_amdgcn_mfma_f32_16x16x32_bf16(wa0, cb0, r2, 0, 0, 0);
    r2 = __builtin_amdgcn_mfma_f32_16x16x32_bf16(wa1, cb1, r2, 0, 0, 0);
    float4 o;
    o.x = fmaxf(r2[0] + b2s[t2 * 16 + lg * 4 + 0], 0.f);
    o.y = fmaxf(r2[1] + b2s[t2 * 16 + lg * 4 + 1], 0.f);
    o.z = fmaxf(r2[2] + b2s[t2 * 16 + lg * 4 + 2], 0.f);
    o.w = fmaxf(r2[3] + b2s[t2 * 16 + lg * 4 + 3], 0.f);
    *(float4*)(orow + t2 * 16 + lg * 4) = o;
  }
}

extern "C" void kernel_launch(void* const* d_in, const int* in_sizes, int n_in,
                              void* d_out, int out_size, void* d_ws, size_t ws_size,
                              hipStream_t stream) {
  const float* vfeat = (const float*)d_in[0];
  const float* v3d = (const float*)d_in[1];
  const float* img = (const float*)d_in[2];
  const int* vx = (const int*)d_in[3];
  const int* vy = (const int*)d_in[4];
  const float* qw = (const float*)d_in[5];
  const float* qb = (const float*)d_in[6];
  const float* kw = (const float*)d_in[7];
  const float* kb = (const float*)d_in[8];
  const float* vw = (const float*)d_in[9];
  const float* vb = (const float*)d_in[10];
  const float* ow = (const float*)d_in[11];
  const float* ob = (const float*)d_in[12];
  const float* fc = (const float*)d_in[13];
  float* out = (float*)d_out;

  char* ws = (char*)d_ws;
  unsigned short* Qb = (unsigned short*)ws;
  unsigned short* Kb = Qb + (size_t)BB * NV * CC;
  unsigned short* VTb = Kb + (size_t)BB * NV * CC;
  float* W2 = (float*)(VTb + (size_t)BB * NV * CC);
  float* b2 = W2 + CC * CC;

  kw2<<<16, 256, 0, stream>>>(ow, ob, fc, W2, b2);
  kprep<<<256, 256, 0, stream>>>(vfeat, v3d, img, vx, vy, qw, qb, kw, kb, vw, vb,
                                 out, Qb, Kb, VTb);
  kattn<<<256, 256, 0, stream>>>(Qb, Kb, VTb, W2, b2, out);
}

// Round 4
// 127.456 us; speedup vs baseline: 2.2217x; 1.1978x over previous
//
#include <hip/hip_runtime.h>

#define BB 4
#define NV 4096
#define BN (BB * NV)
#define CC 64
#define HH 376
#define WW 1240
#define HW (HH * WW)
#define LDT 72          // padded LDS row stride (ushorts)
#define NSPLIT 4
#define TILES 16        // 16 tiles x 64 keys = 1024 keys per split
#define QSCALE 0.1803368801111244f  // (1/8) * log2(e)

typedef __bf16 bf16x8 __attribute__((ext_vector_type(8)));
typedef __bf16 bf16x4 __attribute__((ext_vector_type(4)));
typedef __bf16 bf16x2 __attribute__((ext_vector_type(2)));
typedef float  f32x4  __attribute__((ext_vector_type(4)));

// ---------------- W2 = fc_w @ o_w (bf16), b2 = fc_w @ o_b ----------------
__global__ __launch_bounds__(256) void kw2(const float* __restrict__ ow,
                                           const float* __restrict__ ob,
                                           const float* __restrict__ fc,
                                           unsigned short* __restrict__ W2b,
                                           float* __restrict__ b2) {
  int idx = blockIdx.x * blockDim.x + threadIdx.x;
  if (idx >= CC * CC) return;
  int i = idx >> 6, j = idx & 63;
  float acc = 0.f;
  for (int k = 0; k < CC; ++k) acc += fc[i * CC + k] * ow[k * CC + j];
  ((__bf16*)W2b)[idx] = (__bf16)acc;
  if (idx < CC) {
    float a = 0.f;
    for (int k = 0; k < CC; ++k) a += fc[idx * CC + k] * ob[k];
    b2[idx] = a;
  }
}

// ---------------- prep: gather + Q/K/V projections + passthrough ----------------
// 256 threads/block, 32 voxels/block, 8 threads per voxel (8-channel slice each).
__global__ __launch_bounds__(256) void kprep(
    const float* __restrict__ vfeat, const float* __restrict__ v3d,
    const float* __restrict__ img, const int* __restrict__ vx,
    const int* __restrict__ vy, const float* __restrict__ qw,
    const float* __restrict__ qb, const float* __restrict__ kw,
    const float* __restrict__ kb, const float* __restrict__ vw,
    const float* __restrict__ vb, float* __restrict__ out,
    unsigned short* __restrict__ Qb, unsigned short* __restrict__ Kb,
    unsigned short* __restrict__ VTb) {
  __shared__ float VfS[32][68];
  __shared__ float CamS[32][68];
  const int tid = threadIdx.x;
  const int vl = tid >> 3;   // voxel-local 0..31
  const int p = tid & 7;     // channel-slice 0..7
  const int gv = blockIdx.x * 32 + vl;
  const int b = gv >> 12, n = gv & (NV - 1);
  const size_t row = (size_t)b * NV + n;

  // vfeat slice: passthrough + LDS stash (8 floats)
  {
    const float4* vf4 = (const float4*)(vfeat + row * CC) + p * 2;
    float4* o4 = (float4*)(out + row * 128) + p * 2;
    float4* s4 = (float4*)&VfS[vl][p * 8];
#pragma unroll
    for (int i = 0; i < 2; ++i) { float4 t = vf4[i]; o4[i] = t; s4[i] = t; }
  }

  // camera gather, channels [8p, 8p+8)
  {
    int x = vx[row], y = vy[row];
    bool valid = (x >= 0) & (x < WW) & (y >= 0) & (y < HH);
    int xs = valid ? x : 0, ys = valid ? y : 0;
    const float* ib = img + ((size_t)b * CC + p * 8) * (size_t)HW + (size_t)ys * WW + xs;
#pragma unroll
    for (int i = 0; i < 8; ++i) {
      float cv = ib[(size_t)i * HW];
      CamS[vl][p * 8 + i] = valid ? cv : 0.f;
    }
  }

  // K projection, channels [8p, 8p+8)
  {
    float a0 = v3d[row * 3 + 0], a1 = v3d[row * 3 + 1], a2 = v3d[row * 3 + 2];
#pragma unroll
    for (int cc = 0; cc < 8; cc += 2) {
      int c = p * 8 + cc;
      float k0 = fmaf(a0, kw[c * 3 + 0], fmaf(a1, kw[c * 3 + 1], fmaf(a2, kw[c * 3 + 2], kb[c])));
      float k1 = fmaf(a0, kw[c * 3 + 3], fmaf(a1, kw[c * 3 + 4], fmaf(a2, kw[c * 3 + 5], kb[c + 1])));
      bf16x2 kp; kp[0] = (__bf16)k0; kp[1] = (__bf16)k1;
      *(bf16x2*)(Kb + row * CC + c) = kp;
    }
  }
  __syncthreads();

  // V projection, output channels [8p, 8p+8), store transposed bf16
  {
    f32x4 vr[16];
#pragma unroll
    for (int i = 0; i < 16; ++i) vr[i] = *(const f32x4*)&VfS[vl][i * 4];
#pragma unroll
    for (int cc = 0; cc < 8; ++cc) {
      int c = p * 8 + cc;
      const float4* w4 = (const float4*)(vw + c * CC);
      float acc = vb[c];
#pragma unroll
      for (int j = 0; j < 16; ++j) {
        float4 w = w4[j];
        acc = fmaf(vr[j][0], w.x, fmaf(vr[j][1], w.y, fmaf(vr[j][2], w.z, fmaf(vr[j][3], w.w, acc))));
      }
      ((__bf16*)VTb)[((size_t)b * CC + c) * NV + n] = (__bf16)acc;
    }
  }

  // Q projection (scaled by log2e/8), output channels [8p, 8p+8)
  {
    f32x4 cr[16];
#pragma unroll
    for (int i = 0; i < 16; ++i) cr[i] = *(const f32x4*)&CamS[vl][i * 4];
#pragma unroll
    for (int cc = 0; cc < 8; cc += 2) {
      int c = p * 8 + cc;
      float acc0 = qb[c], acc1 = qb[c + 1];
      const float4* w0 = (const float4*)(qw + c * CC);
      const float4* w1 = (const float4*)(qw + (c + 1) * CC);
#pragma unroll
      for (int j = 0; j < 16; ++j) {
        f32x4 a = cr[j];
        float4 wa = w0[j], wb = w1[j];
        acc0 = fmaf(a[0], wa.x, fmaf(a[1], wa.y, fmaf(a[2], wa.z, fmaf(a[3], wa.w, acc0))));
        acc1 = fmaf(a[0], wb.x, fmaf(a[1], wb.y, fmaf(a[2], wb.z, fmaf(a[3], wb.w, acc1))));
      }
      bf16x2 qp2; qp2[0] = (__bf16)(acc0 * QSCALE); qp2[1] = (__bf16)(acc1 * QSCALE);
      *(bf16x2*)(Qb + row * CC + c) = qp2;
    }
  }
}

// ---------------- flash attention, split-K x4, partial outputs ----------------
// grid 1024 = 4 batch x 64 q-chunks x 4 splits; 4 waves/block; 3 blocks/CU.
__global__ __launch_bounds__(256, 3) void kattn(const unsigned short* __restrict__ Qb,
                                                const unsigned short* __restrict__ Kb,
                                                const unsigned short* __restrict__ VTb,
                                                float* __restrict__ Op,
                                                float* __restrict__ ml) {
  __shared__ unsigned short Ks[2][64 * LDT];
  __shared__ unsigned short Vs[2][64 * LDT];
  __shared__ unsigned short Ps[4][16 * LDT];

  const int bid = blockIdx.x;
  const int xcd = bid & 7;
  const int idx = bid >> 3;          // 0..127
  const int combo = xcd * 2 + (idx >> 6);  // 0..15 -> (b, split)
  const int qc = idx & 63;
  const int b = combo >> 2;
  const int sp = combo & 3;
  const int q0 = qc * 64;
  const int key0 = sp * (TILES * 64);

  const int tid = threadIdx.x;
  const int wid = tid >> 6;
  const int lane = tid & 63;
  const int lq = lane & 15;
  const int lg = lane >> 4;

  const int srow = tid >> 2;         // 0..63
  const int scol = (tid & 3) * 16;   // 16-ushort slot (2x uint4)

  const unsigned short* qp = Qb + ((size_t)b * NV + q0 + wid * 16 + lq) * CC + lg * 8;
  bf16x8 qf0 = *(const bf16x8*)(qp);
  bf16x8 qf1 = *(const bf16x8*)(qp + 32);

  const f32x4 vzero = {0.f, 0.f, 0.f, 0.f};
  float m_run = -1e30f, l_run = 0.f;
  f32x4 oacc[4];
#pragma unroll
  for (int t = 0; t < 4; ++t) oacc[t] = vzero;

  const unsigned short* kgb = Kb + (size_t)b * NV * CC;
  const unsigned short* vgb = VTb + (size_t)b * CC * NV;

  uint4 kr0, kr1, vr0, vr1;
  {  // prologue: stage tile 0
    const uint4* ksrc = (const uint4*)(kgb + (size_t)(key0 + srow) * CC + scol);
    const uint4* vsrc = (const uint4*)(vgb + (size_t)srow * NV + key0 + scol);
    kr0 = ksrc[0]; kr1 = ksrc[1];
    vr0 = vsrc[0]; vr1 = vsrc[1];
    uint4* kdst = (uint4*)&Ks[0][srow * LDT + scol];
    uint4* vdst = (uint4*)&Vs[0][srow * LDT + scol];
    kdst[0] = kr0; kdst[1] = kr1;
    vdst[0] = vr0; vdst[1] = vr1;
  }
  __syncthreads();

  int cur = 0;
  for (int tt = 0; tt < TILES; ++tt) {
    if (tt + 1 < TILES) {  // issue next tile's loads early
      int k0 = key0 + (tt + 1) * 64;
      const uint4* ksrc = (const uint4*)(kgb + (size_t)(k0 + srow) * CC + scol);
      const uint4* vsrc = (const uint4*)(vgb + (size_t)srow * NV + k0 + scol);
      kr0 = ksrc[0]; kr1 = ksrc[1];
      vr0 = vsrc[0]; vr1 = vsrc[1];
    }

    // S^T = K . Q^T (scores already in log2 domain via Q scale)
    f32x4 s[4];
#pragma unroll
    for (int t = 0; t < 4; ++t) s[t] = vzero;
#pragma unroll
    for (int t = 0; t < 4; ++t) {
      bf16x8 ka0 = *(const bf16x8*)&Ks[cur][(t * 16 + lq) * LDT + lg * 8];
      bf16x8 ka1 = *(const bf16x8*)&Ks[cur][(t * 16 + lq) * LDT + 32 + lg * 8];
      s[t] = __builtin_amdgcn_mfma_f32_16x16x32_bf16(ka0, qf0, s[t], 0, 0, 0);
      s[t] = __builtin_amdgcn_mfma_f32_16x16x32_bf16(ka1, qf1, s[t], 0, 0, 0);
    }

    // tile max (max3-friendly)
    float t0m = fmaxf(fmaxf(s[0][0], s[0][1]), fmaxf(s[0][2], s[0][3]));
    float t1m = fmaxf(fmaxf(s[1][0], s[1][1]), fmaxf(s[1][2], s[1][3]));
    float t2m = fmaxf(fmaxf(s[2][0], s[2][1]), fmaxf(s[2][2], s[2][3]));
    float t3m = fmaxf(fmaxf(s[3][0], s[3][1]), fmaxf(s[3][2], s[3][3]));
    float tmax = fmaxf(fmaxf(t0m, t1m), fmaxf(t2m, t3m));
    tmax = fmaxf(tmax, __shfl_xor(tmax, 16));
    tmax = fmaxf(tmax, __shfl_xor(tmax, 32));

    // defer-max: rescale only when some query's max grew by >8 (log2 domain)
    if (!__all(tmax <= m_run + 8.f)) {
      float m_new = fmaxf(m_run, tmax);
      float sc = __builtin_amdgcn_exp2f(m_run - m_new);
      l_run *= sc;
      m_run = m_new;
#pragma unroll
      for (int r = 0; r < 4; ++r) {
        float scr = __shfl(sc, lg * 4 + r);
#pragma unroll
        for (int t = 0; t < 4; ++t) oacc[t][r] *= scr;
      }
    }

    float psum = 0.f;
#pragma unroll
    for (int t = 0; t < 4; ++t) {
      float p0 = __builtin_amdgcn_exp2f(s[t][0] - m_run);
      float p1 = __builtin_amdgcn_exp2f(s[t][1] - m_run);
      float p2 = __builtin_amdgcn_exp2f(s[t][2] - m_run);
      float p3 = __builtin_amdgcn_exp2f(s[t][3] - m_run);
      psum += (p0 + p1) + (p2 + p3);
      bf16x4 pk;
      pk[0] = (__bf16)p0; pk[1] = (__bf16)p1; pk[2] = (__bf16)p2; pk[3] = (__bf16)p3;
      *(bf16x4*)&Ps[wid][lq * LDT + t * 16 + lg * 4] = pk;
    }
    psum += __shfl_xor(psum, 16);
    psum += __shfl_xor(psum, 32);
    l_run += psum;

    // O += P . V
#pragma unroll
    for (int ks = 0; ks < 2; ++ks) {
      bf16x8 pa = *(const bf16x8*)&Ps[wid][lq * LDT + ks * 32 + lg * 8];
#pragma unroll
      for (int t = 0; t < 4; ++t) {
        bf16x8 vbf = *(const bf16x8*)&Vs[cur][(t * 16 + lq) * LDT + ks * 32 + lg * 8];
        oacc[t] = __builtin_amdgcn_mfma_f32_16x16x32_bf16(pa, vbf, oacc[t], 0, 0, 0);
      }
    }

    if (tt + 1 < TILES) {
      uint4* kdst = (uint4*)&Ks[cur ^ 1][srow * LDT + scol];
      uint4* vdst = (uint4*)&Vs[cur ^ 1][srow * LDT + scol];
      kdst[0] = kr0; kdst[1] = kr1;
      vdst[0] = vr0; vdst[1] = vr1;
    }
    __syncthreads();
    cur ^= 1;
  }

  // write unnormalized partial O and (m,l)
  const size_t obase = (size_t)sp * BN + (size_t)b * NV + q0 + wid * 16;
#pragma unroll
  for (int r = 0; r < 4; ++r) {
    float* op = Op + (obase + lg * 4 + r) * CC + lq;
#pragma unroll
    for (int t = 0; t < 4; ++t) op[t * 16] = oacc[t][r];
  }
  if (lg == 0) {
    float2 t2; t2.x = m_run; t2.y = l_run;
    ((float2*)ml)[obase + lq] = t2;
  }
}

// ---------------- merge 4 partials + fused epilogue ----------------
__global__ __launch_bounds__(256) void kmerge(const float* __restrict__ Op,
                                              const float* __restrict__ ml,
                                              const unsigned short* __restrict__ W2b,
                                              const float* __restrict__ b2f,
                                              float* __restrict__ out) {
  __shared__ unsigned short W2s[64 * LDT];
  __shared__ float b2s[64];
  const int tid = threadIdx.x;
  const int wid = tid >> 6;
  const int lane = tid & 63;
  const int lq = lane & 15;
  const int lg = lane >> 4;
  const int srow = tid >> 2;
  const int scol = (tid & 3) * 16;

  {
    const uint4* ws = (const uint4*)(W2b + srow * CC + scol);
    uint4* wd = (uint4*)&W2s[srow * LDT + scol];
    wd[0] = ws[0]; wd[1] = ws[1];
    if (tid < 64) b2s[tid] = b2f[tid];
  }
  __syncthreads();

  const int row = blockIdx.x * 64 + wid * 16 + lq;

  float mv[NSPLIT], lv[NSPLIT], w[NSPLIT];
#pragma unroll
  for (int s = 0; s < NSPLIT; ++s) {
    float2 t = ((const float2*)ml)[(size_t)s * BN + row];
    mv[s] = t.x; lv[s] = t.y;
  }
  float mstar = fmaxf(fmaxf(mv[0], mv[1]), fmaxf(mv[2], mv[3]));
  float lstar = 0.f;
#pragma unroll
  for (int s = 0; s < NSPLIT; ++s) {
    w[s] = __builtin_amdgcn_exp2f(mv[s] - mstar);
    lstar = fmaf(w[s], lv[s], lstar);
  }

  float ctx[16];
#pragma unroll
  for (int j = 0; j < 16; ++j) ctx[j] = 0.f;
#pragma unroll
  for (int s = 0; s < NSPLIT; ++s) {
    const float4* op4 = (const float4*)(Op + ((size_t)s * BN + row) * CC);
    float4 a0 = op4[lg * 2], a1 = op4[lg * 2 + 1];
    float4 b0 = op4[8 + lg * 2], b1 = op4[8 + lg * 2 + 1];
    float ws_ = w[s];
    ctx[0]  = fmaf(ws_, a0.x, ctx[0]);  ctx[1]  = fmaf(ws_, a0.y, ctx[1]);
    ctx[2]  = fmaf(ws_, a0.z, ctx[2]);  ctx[3]  = fmaf(ws_, a0.w, ctx[3]);
    ctx[4]  = fmaf(ws_, a1.x, ctx[4]);  ctx[5]  = fmaf(ws_, a1.y, ctx[5]);
    ctx[6]  = fmaf(ws_, a1.z, ctx[6]);  ctx[7]  = fmaf(ws_, a1.w, ctx[7]);
    ctx[8]  = fmaf(ws_, b0.x, ctx[8]);  ctx[9]  = fmaf(ws_, b0.y, ctx[9]);
    ctx[10] = fmaf(ws_, b0.z, ctx[10]); ctx[11] = fmaf(ws_, b0.w, ctx[11]);
    ctx[12] = fmaf(ws_, b1.x, ctx[12]); ctx[13] = fmaf(ws_, b1.y, ctx[13]);
    ctx[14] = fmaf(ws_, b1.z, ctx[14]); ctx[15] = fmaf(ws_, b1.w, ctx[15]);
  }
  float inv = 1.f / lstar;
  bf16x8 cb0, cb1;
#pragma unroll
  for (int j = 0; j < 8; ++j) {
    cb0[j] = (__bf16)(ctx[j] * inv);
    cb1[j] = (__bf16)(ctx[8 + j] * inv);
  }

  const f32x4 vzero = {0.f, 0.f, 0.f, 0.f};
  float* orow = out + (size_t)row * 128 + 64;
#pragma unroll
  for (int t2 = 0; t2 < 4; ++t2) {
    bf16x8 wa0 = *(const bf16x8*)&W2s[(t2 * 16 + lq) * LDT + lg * 8];
    bf16x8 wa1 = *(const bf16x8*)&W2s[(t2 * 16 + lq) * LDT + 32 + lg * 8];
    f32x4 r2 = vzero;
    r2 = __builtin_amdgcn_mfma_f32_16x16x32_bf16(wa0, cb0, r2, 0, 0, 0);
    r2 = __builtin_amdgcn_mfma_f32_16x16x32_bf16(wa1, cb1, r2, 0, 0, 0);
    float4 o;
    o.x = fmaxf(r2[0] + b2s[t2 * 16 + lg * 4 + 0], 0.f);
    o.y = fmaxf(r2[1] + b2s[t2 * 16 + lg * 4 + 1], 0.f);
    o.z = fmaxf(r2[2] + b2s[t2 * 16 + lg * 4 + 2], 0.f);
    o.w = fmaxf(r2[3] + b2s[t2 * 16 + lg * 4 + 3], 0.f);
    *(float4*)(orow + t2 * 16 + lg * 4) = o;
  }
}

extern "C" void kernel_launch(void* const* d_in, const int* in_sizes, int n_in,
                              void* d_out, int out_size, void* d_ws, size_t ws_size,
                              hipStream_t stream) {
  const float* vfeat = (const float*)d_in[0];
  const float* v3d = (const float*)d_in[1];
  const float* img = (const float*)d_in[2];
  const int* vx = (const int*)d_in[3];
  const int* vy = (const int*)d_in[4];
  const float* qw = (const float*)d_in[5];
  const float* qb = (const float*)d_in[6];
  const float* kw = (const float*)d_in[7];
  const float* kb = (const float*)d_in[8];
  const float* vw = (const float*)d_in[9];
  const float* vb = (const float*)d_in[10];
  const float* ow = (const float*)d_in[11];
  const float* ob = (const float*)d_in[12];
  const float* fc = (const float*)d_in[13];
  float* out = (float*)d_out;

  char* ws = (char*)d_ws;
  unsigned short* Qb = (unsigned short*)(ws);                    // 2 MB
  unsigned short* Kb = (unsigned short*)(ws + (2u << 20));       // 2 MB
  unsigned short* VTb = (unsigned short*)(ws + (4u << 20));      // 2 MB
  float* Op = (float*)(ws + (6u << 20));                         // 16 MB
  float* ml = (float*)(ws + (22u << 20));                        // 512 KB
  unsigned short* W2b = (unsigned short*)(ws + (23u << 20));     // 8 KB
  float* b2 = (float*)(ws + (23u << 20) + 8192);

  kw2<<<16, 256, 0, stream>>>(ow, ob, fc, W2b, b2);
  kprep<<<512, 256, 0, stream>>>(vfeat, v3d, img, vx, vy, qw, qb, kw, kb, vw, vb,
                                 out, Qb, Kb, VTb);
  kattn<<<1024, 256, 0, stream>>>(Qb, Kb, VTb, Op, ml);
  kmerge<<<256, 256, 0, stream>>>(Op, ml, W2b, b2, out);
}

// Round 5
// 96.770 us; speedup vs baseline: 2.9262x; 1.3171x over previous
//
#include <hip/hip_runtime.h>

#define BB 4
#define NV 4096
#define BN (BB * NV)
#define CC 64
#define HH 376
#define WW 1240
#define HW (HH * WW)
#define LDT 72          // V/P LDS row stride (ushorts)
#define LDK 36          // K32 LDS row stride (ushorts)
#define NSPLIT 4
#define TILES 16        // 16 tiles x 64 keys = 1024 keys per split
#define QSCALE 0.1803368801111244f  // (1/8) * log2(e)

typedef __bf16 bf16x8 __attribute__((ext_vector_type(8)));
typedef __bf16 bf16x4 __attribute__((ext_vector_type(4)));
typedef float  f32x4  __attribute__((ext_vector_type(4)));

// ---- kw2: W2 = fc@o_w (bf16), b2 = fc@o_b, Wqk3 = q_w^T@k_w, bqk3 = q_b@k_w ----
__global__ __launch_bounds__(256) void kw2(const float* __restrict__ qw,
                                           const float* __restrict__ qb,
                                           const float* __restrict__ kw,
                                           const float* __restrict__ ow,
                                           const float* __restrict__ ob,
                                           const float* __restrict__ fc,
                                           unsigned short* __restrict__ W2b,
                                           float* __restrict__ b2,
                                           float* __restrict__ Wqk3,
                                           float* __restrict__ bqk3) {
  int idx = blockIdx.x * blockDim.x + threadIdx.x;
  if (idx >= CC * CC) return;
  int i = idx >> 6, j = idx & 63;
  float acc = 0.f;
  for (int k = 0; k < CC; ++k) acc += fc[i * CC + k] * ow[k * CC + j];
  ((__bf16*)W2b)[idx] = (__bf16)acc;
  if (idx < CC) {
    float a = 0.f;
    for (int k = 0; k < CC; ++k) a += fc[idx * CC + k] * ob[k];
    b2[idx] = a;
  }
  if (idx < CC * 3) {
    int jj = idx / 3, d = idx - jj * 3;
    float a = 0.f;
    for (int k = 0; k < CC; ++k) a += qw[k * CC + jj] * kw[k * 3 + d];
    Wqk3[idx] = a;
  }
  if (idx < 3) {
    float a = 0.f;
    for (int k = 0; k < CC; ++k) a += qb[k] * kw[k * 3 + idx];
    bqk3[idx] = a;
  }
}

// ---------------- prep: gather + Q(3)/V projections + passthrough ----------------
// 256 threads/block, 32 voxels/block, 8 threads per voxel.
__global__ __launch_bounds__(256) void kprep(
    const float* __restrict__ vfeat, const float* __restrict__ v3d,
    const float* __restrict__ img, const int* __restrict__ vx,
    const int* __restrict__ vy, const float* __restrict__ Wqk3,
    const float* __restrict__ bqk3, const float* __restrict__ vw,
    const float* __restrict__ vb, float* __restrict__ out,
    unsigned short* __restrict__ Qp, unsigned short* __restrict__ K32,
    unsigned short* __restrict__ VTb) {
  __shared__ float VfS[32][68];
  __shared__ float CamS[32][68];
  const int tid = threadIdx.x;
  const int vl = tid >> 3;   // voxel-local 0..31
  const int p = tid & 7;     // slice 0..7
  const int gv = blockIdx.x * 32 + vl;
  const int b = gv >> 12, n = gv & (NV - 1);
  const size_t row = (size_t)b * NV + n;

  // vfeat slice: passthrough + LDS stash
  {
    const float4* vf4 = (const float4*)(vfeat + row * CC) + p * 2;
    float4* o4 = (float4*)(out + row * 128) + p * 2;
    float4* s4 = (float4*)&VfS[vl][p * 8];
#pragma unroll
    for (int i = 0; i < 2; ++i) { float4 t = vf4[i]; o4[i] = t; s4[i] = t; }
  }

  // camera gather, channels [8p, 8p+8)
  {
    int x = vx[row], y = vy[row];
    bool valid = (x >= 0) & (x < WW) & (y >= 0) & (y < HH);
    int xs = valid ? x : 0, ys = valid ? y : 0;
    const float* ib = img + ((size_t)b * CC + p * 8) * (size_t)HW + (size_t)ys * WW + xs;
#pragma unroll
    for (int i = 0; i < 8; ++i) {
      float cv = ib[(size_t)i * HW];
      CamS[vl][p * 8 + i] = valid ? cv : 0.f;
    }
  }

  // K32: raw 3d coords, bf16, padded to 32
  if (p == 0) {
    float c0 = v3d[row * 3 + 0], c1 = v3d[row * 3 + 1], c2 = v3d[row * 3 + 2];
    bf16x8 kp = {(__bf16)c0, (__bf16)c1, (__bf16)c2,
                 (__bf16)0.f, (__bf16)0.f, (__bf16)0.f, (__bf16)0.f, (__bf16)0.f};
    *(bf16x8*)(K32 + row * 32) = kp;
  } else if (p < 4) {
    bf16x8 z = {(__bf16)0.f, (__bf16)0.f, (__bf16)0.f, (__bf16)0.f,
                (__bf16)0.f, (__bf16)0.f, (__bf16)0.f, (__bf16)0.f};
    *(bf16x8*)(K32 + row * 32 + p * 8) = z;
  }
  __syncthreads();

  // V projection, output channels [8p, 8p+8), store transposed bf16
  {
    f32x4 vr[16];
#pragma unroll
    for (int i = 0; i < 16; ++i) vr[i] = *(const f32x4*)&VfS[vl][i * 4];
#pragma unroll
    for (int cc = 0; cc < 8; ++cc) {
      int c = p * 8 + cc;
      const float4* w4 = (const float4*)(vw + c * CC);
      float acc = vb[c];
#pragma unroll
      for (int j = 0; j < 16; ++j) {
        float4 w = w4[j];
        acc = fmaf(vr[j][0], w.x, fmaf(vr[j][1], w.y, fmaf(vr[j][2], w.z, fmaf(vr[j][3], w.w, acc))));
      }
      ((__bf16*)VTb)[((size_t)b * CC + c) * NV + n] = (__bf16)acc;
    }
  }

  // Qp: qp3 = QSCALE*(cam @ Wqk3 + bqk3), bf16, padded to 32
  if (p == 0) {
    float q0 = bqk3[0], q1 = bqk3[1], q2 = bqk3[2];
#pragma unroll 8
    for (int j = 0; j < CC; ++j) {
      float c = CamS[vl][j];
      q0 = fmaf(c, Wqk3[j * 3 + 0], q0);
      q1 = fmaf(c, Wqk3[j * 3 + 1], q1);
      q2 = fmaf(c, Wqk3[j * 3 + 2], q2);
    }
    bf16x8 qp = {(__bf16)(q0 * QSCALE), (__bf16)(q1 * QSCALE), (__bf16)(q2 * QSCALE),
                 (__bf16)0.f, (__bf16)0.f, (__bf16)0.f, (__bf16)0.f, (__bf16)0.f};
    *(bf16x8*)(Qp + row * 32) = qp;
  } else if (p < 4) {
    bf16x8 z = {(__bf16)0.f, (__bf16)0.f, (__bf16)0.f, (__bf16)0.f,
                (__bf16)0.f, (__bf16)0.f, (__bf16)0.f, (__bf16)0.f};
    *(bf16x8*)(Qp + row * 32 + p * 8) = z;
  }
}

// ---------------- flash attention, split-K x4, rank-3 scores via K=32 MFMA ----------------
// grid 1024 = 4 batch x 4 splits x 64 q-chunks; 4 waves/block; 4 blocks/CU.
__global__ __launch_bounds__(256, 4) void kattn(const unsigned short* __restrict__ Qp,
                                                const unsigned short* __restrict__ K32,
                                                const unsigned short* __restrict__ VTb,
                                                unsigned short* __restrict__ Opb,
                                                float* __restrict__ ml) {
  __shared__ unsigned short Ks[2][64 * LDK];
  __shared__ unsigned short Vs[2][64 * LDT];
  __shared__ unsigned short Ps[4][16 * LDT];

  const int bid = blockIdx.x;
  const int xcd = bid & 7;
  const int idx = bid >> 3;                // 0..127
  const int combo = xcd * 2 + (idx >> 6);  // 0..15 -> (b, split)
  const int qc = idx & 63;
  const int b = combo >> 2;
  const int sp = combo & 3;
  const int q0 = qc * 64;
  const int key0 = sp * (TILES * 64);

  const int tid = threadIdx.x;
  const int wid = tid >> 6;
  const int lane = tid & 63;
  const int lq = lane & 15;
  const int lg = lane >> 4;

  const int srow = tid >> 2;         // 0..63
  const int scol = (tid & 3) * 16;   // V slot (2x uint4)
  const int kcol = (tid & 3) * 8;    // K slot (1x uint4)

  bf16x8 qf = *(const bf16x8*)(Qp + ((size_t)b * NV + q0 + wid * 16 + lq) * 32 + lg * 8);

  const f32x4 vzero = {0.f, 0.f, 0.f, 0.f};
  float m_run = -1e30f, l_run = 0.f;
  f32x4 oacc[4];
#pragma unroll
  for (int t = 0; t < 4; ++t) oacc[t] = vzero;

  const unsigned short* kgb = K32 + ((size_t)b * NV) * 32;
  const unsigned short* vgb = VTb + (size_t)b * CC * NV;

  uint4 kq, vr0, vr1;
  {  // prologue: stage tile 0
    kq = *(const uint4*)(kgb + (size_t)(key0 + srow) * 32 + kcol);
    const uint4* vsrc = (const uint4*)(vgb + (size_t)srow * NV + key0 + scol);
    vr0 = vsrc[0]; vr1 = vsrc[1];
    *(uint4*)&Ks[0][srow * LDK + kcol] = kq;
    uint4* vdst = (uint4*)&Vs[0][srow * LDT + scol];
    vdst[0] = vr0; vdst[1] = vr1;
  }
  __syncthreads();

  int cur = 0;
  for (int tt = 0; tt < TILES; ++tt) {
    if (tt + 1 < TILES) {  // issue next tile's loads early
      int k0 = key0 + (tt + 1) * 64;
      kq = *(const uint4*)(kgb + (size_t)(k0 + srow) * 32 + kcol);
      const uint4* vsrc = (const uint4*)(vgb + (size_t)srow * NV + k0 + scol);
      vr0 = vsrc[0]; vr1 = vsrc[1];
    }

    // S^T = K . Q^T (log2 domain; K-dim 32 = 3 coords + zero pad)
    f32x4 s[4];
#pragma unroll
    for (int t = 0; t < 4; ++t) {
      bf16x8 ka = *(const bf16x8*)&Ks[cur][(t * 16 + lq) * LDK + lg * 8];
      s[t] = __builtin_amdgcn_mfma_f32_16x16x32_bf16(ka, qf, vzero, 0, 0, 0);
    }

    // tile max
    float t0m = fmaxf(fmaxf(s[0][0], s[0][1]), fmaxf(s[0][2], s[0][3]));
    float t1m = fmaxf(fmaxf(s[1][0], s[1][1]), fmaxf(s[1][2], s[1][3]));
    float t2m = fmaxf(fmaxf(s[2][0], s[2][1]), fmaxf(s[2][2], s[2][3]));
    float t3m = fmaxf(fmaxf(s[3][0], s[3][1]), fmaxf(s[3][2], s[3][3]));
    float tmax = fmaxf(fmaxf(t0m, t1m), fmaxf(t2m, t3m));
    tmax = fmaxf(tmax, __shfl_xor(tmax, 16));
    tmax = fmaxf(tmax, __shfl_xor(tmax, 32));

    // defer-max: rescale only when some query's max grew by >8 (log2 domain)
    if (!__all(tmax <= m_run + 8.f)) {
      float m_new = fmaxf(m_run, tmax);
      float sc = __builtin_amdgcn_exp2f(m_run - m_new);
      l_run *= sc;
      m_run = m_new;
#pragma unroll
      for (int r = 0; r < 4; ++r) {
        float scr = __shfl(sc, lg * 4 + r);
#pragma unroll
        for (int t = 0; t < 4; ++t) oacc[t][r] *= scr;
      }
    }

    float psum = 0.f;
#pragma unroll
    for (int t = 0; t < 4; ++t) {
      float p0 = __builtin_amdgcn_exp2f(s[t][0] - m_run);
      float p1 = __builtin_amdgcn_exp2f(s[t][1] - m_run);
      float p2 = __builtin_amdgcn_exp2f(s[t][2] - m_run);
      float p3 = __builtin_amdgcn_exp2f(s[t][3] - m_run);
      psum += (p0 + p1) + (p2 + p3);
      bf16x4 pk;
      pk[0] = (__bf16)p0; pk[1] = (__bf16)p1; pk[2] = (__bf16)p2; pk[3] = (__bf16)p3;
      *(bf16x4*)&Ps[wid][lq * LDT + t * 16 + lg * 4] = pk;
    }
    psum += __shfl_xor(psum, 16);
    psum += __shfl_xor(psum, 32);
    l_run += psum;

    // O += P . V
#pragma unroll
    for (int ks = 0; ks < 2; ++ks) {
      bf16x8 pa = *(const bf16x8*)&Ps[wid][lq * LDT + ks * 32 + lg * 8];
#pragma unroll
      for (int t = 0; t < 4; ++t) {
        bf16x8 vbf = *(const bf16x8*)&Vs[cur][(t * 16 + lq) * LDT + ks * 32 + lg * 8];
        oacc[t] = __builtin_amdgcn_mfma_f32_16x16x32_bf16(pa, vbf, oacc[t], 0, 0, 0);
      }
    }

    if (tt + 1 < TILES) {
      *(uint4*)&Ks[cur ^ 1][srow * LDK + kcol] = kq;
      uint4* vdst = (uint4*)&Vs[cur ^ 1][srow * LDT + scol];
      vdst[0] = vr0; vdst[1] = vr1;
    }
    __syncthreads();
    cur ^= 1;
  }

  // write unnormalized partial O (bf16) and (m,l)
  const size_t obase = (size_t)sp * BN + (size_t)b * NV + q0 + wid * 16;
#pragma unroll
  for (int r = 0; r < 4; ++r) {
    __bf16* op = (__bf16*)Opb + (obase + lg * 4 + r) * CC + lq;
#pragma unroll
    for (int t = 0; t < 4; ++t) op[t * 16] = (__bf16)oacc[t][r];
  }
  if (lg == 0) {
    float2 t2; t2.x = m_run; t2.y = l_run;
    ((float2*)ml)[obase + lq] = t2;
  }
}

// ---------------- merge 4 partials + fused epilogue ----------------
__global__ __launch_bounds__(256) void kmerge(const unsigned short* __restrict__ Opb,
                                              const float* __restrict__ ml,
                                              const unsigned short* __restrict__ W2b,
                                              const float* __restrict__ b2f,
                                              float* __restrict__ out) {
  __shared__ unsigned short W2s[64 * LDT];
  __shared__ float b2s[64];
  const int tid = threadIdx.x;
  const int wid = tid >> 6;
  const int lane = tid & 63;
  const int lq = lane & 15;
  const int lg = lane >> 4;
  const int srow = tid >> 2;
  const int scol = (tid & 3) * 16;

  {
    const uint4* ws = (const uint4*)(W2b + srow * CC + scol);
    uint4* wd = (uint4*)&W2s[srow * LDT + scol];
    wd[0] = ws[0]; wd[1] = ws[1];
    if (tid < 64) b2s[tid] = b2f[tid];
  }
  __syncthreads();

  const int row = blockIdx.x * 64 + wid * 16 + lq;

  float mv[NSPLIT], lv[NSPLIT], w[NSPLIT];
#pragma unroll
  for (int s = 0; s < NSPLIT; ++s) {
    float2 t = ((const float2*)ml)[(size_t)s * BN + row];
    mv[s] = t.x; lv[s] = t.y;
  }
  float mstar = fmaxf(fmaxf(mv[0], mv[1]), fmaxf(mv[2], mv[3]));
  float lstar = 0.f;
#pragma unroll
  for (int s = 0; s < NSPLIT; ++s) {
    w[s] = __builtin_amdgcn_exp2f(mv[s] - mstar);
    lstar = fmaf(w[s], lv[s], lstar);
  }

  float ctx[16];
#pragma unroll
  for (int j = 0; j < 16; ++j) ctx[j] = 0.f;
#pragma unroll
  for (int s = 0; s < NSPLIT; ++s) {
    const __bf16* oprow = (const __bf16*)Opb + ((size_t)s * BN + row) * CC;
    bf16x8 a0 = *(const bf16x8*)(oprow + lg * 8);
    bf16x8 a1 = *(const bf16x8*)(oprow + 32 + lg * 8);
    float ws_ = w[s];
#pragma unroll
    for (int j = 0; j < 8; ++j) {
      ctx[j] = fmaf(ws_, (float)a0[j], ctx[j]);
      ctx[8 + j] = fmaf(ws_, (float)a1[j], ctx[8 + j]);
    }
  }
  float inv = 1.f / lstar;
  bf16x8 cb0, cb1;
#pragma unroll
  for (int j = 0; j < 8; ++j) {
    cb0[j] = (__bf16)(ctx[j] * inv);
    cb1[j] = (__bf16)(ctx[8 + j] * inv);
  }

  const f32x4 vzero = {0.f, 0.f, 0.f, 0.f};
  float* orow = out + (size_t)row * 128 + 64;
#pragma unroll
  for (int t2 = 0; t2 < 4; ++t2) {
    bf16x8 wa0 = *(const bf16x8*)&W2s[(t2 * 16 + lq) * LDT + lg * 8];
    bf16x8 wa1 = *(const bf16x8*)&W2s[(t2 * 16 + lq) * LDT + 32 + lg * 8];
    f32x4 r2 = vzero;
    r2 = __builtin_amdgcn_mfma_f32_16x16x32_bf16(wa0, cb0, r2, 0, 0, 0);
    r2 = __builtin_amdgcn_mfma_f32_16x16x32_bf16(wa1, cb1, r2, 0, 0, 0);
    float4 o;
    o.x = fmaxf(r2[0] + b2s[t2 * 16 + lg * 4 + 0], 0.f);
    o.y = fmaxf(r2[1] + b2s[t2 * 16 + lg * 4 + 1], 0.f);
    o.z = fmaxf(r2[2] + b2s[t2 * 16 + lg * 4 + 2], 0.f);
    o.w = fmaxf(r2[3] + b2s[t2 * 16 + lg * 4 + 3], 0.f);
    *(float4*)(orow + t2 * 16 + lg * 4) = o;
  }
}

extern "C" void kernel_launch(void* const* d_in, const int* in_sizes, int n_in,
                              void* d_out, int out_size, void* d_ws, size_t ws_size,
                              hipStream_t stream) {
  const float* vfeat = (const float*)d_in[0];
  const float* v3d = (const float*)d_in[1];
  const float* img = (const float*)d_in[2];
  const int* vx = (const int*)d_in[3];
  const int* vy = (const int*)d_in[4];
  const float* qw = (const float*)d_in[5];
  const float* qb = (const float*)d_in[6];
  const float* kw = (const float*)d_in[7];
  const float* kb = (const float*)d_in[8];  // cancels in softmax
  const float* vw = (const float*)d_in[9];
  const float* vb = (const float*)d_in[10];
  const float* ow = (const float*)d_in[11];
  const float* ob = (const float*)d_in[12];
  const float* fc = (const float*)d_in[13];
  float* out = (float*)d_out;
  (void)kb;

  char* ws = (char*)d_ws;
  unsigned short* Qp = (unsigned short*)(ws);                    // 1 MB
  unsigned short* K32 = (unsigned short*)(ws + (1u << 20));      // 1 MB
  unsigned short* VTb = (unsigned short*)(ws + (2u << 20));      // 2 MB
  unsigned short* Opb = (unsigned short*)(ws + (4u << 20));      // 8 MB
  float* ml = (float*)(ws + (12u << 20));                        // 512 KB
  unsigned short* W2b = (unsigned short*)(ws + (12u << 20) + (512u << 10));
  float* b2 = (float*)(ws + (12u << 20) + (512u << 10) + 8192);
  float* Wqk3 = b2 + 64;
  float* bqk3 = Wqk3 + 192;

  kw2<<<16, 256, 0, stream>>>(qw, qb, kw, ow, ob, fc, W2b, b2, Wqk3, bqk3);
  kprep<<<512, 256, 0, stream>>>(vfeat, v3d, img, vx, vy, Wqk3, bqk3, vw, vb,
                                 out, Qp, K32, VTb);
  kattn<<<1024, 256, 0, stream>>>(Qp, K32, VTb, Opb, ml);
  kmerge<<<256, 256, 0, stream>>>(Opb, ml, W2b, b2, out);
}